// Round 7
// baseline (256.222 us; speedup 1.0000x reference)
//
#include <hip/hip_runtime.h>

#define NSTEP 2047
#define NB    4096

__device__ __forceinline__ float fexp2(float x) {
    float r; asm("v_exp_f32 %0, %1" : "=v"(r) : "v"(x)); return r;
}
__device__ __forceinline__ float frcp(float x) {
    float r; asm("v_rcp_f32 %0, %1" : "=v"(r) : "v"(x)); return r;
}
template <int CTRL>
__device__ __forceinline__ float qperm(float x) {
    int i = __builtin_bit_cast(int, x);
    i = __builtin_amdgcn_mov_dpp(i, CTRL, 0xF, 0xF, true);
    return __builtin_bit_cast(float, i);
}
#define XOR1  0xB1   // quad_perm [1,0,3,2]
#define XOR2  0x4E   // quad_perm [2,3,0,1]
#define ROT1  0x39   // quad_perm [1,2,3,0]
#define ROT3  0x93   // quad_perm [3,0,1,2]
#define RSHR4 0x114  // row_shr:4  lane l <- l-4 (lanes 4-7 read 0-3)
#define RSHL4 0x104  // row_shl:4  lane l <- l+4 (lanes 0-3 read 4-7)

__global__ __launch_bounds__(64, 1)
void cstr_kernel(const float* __restrict__ w, const float* __restrict__ Kp,
                 const float* __restrict__ Lp, const float* __restrict__ Mp,
                 const float* __restrict__ Mop, float* __restrict__ out)
{
    const int tid = blockIdx.x * 64 + threadIdx.x;   // 0..32767
    const int o   = tid & 7;                         // octet lane
    const int b   = tid >> 3;                        // sample

    constexpr float Hc  = 0.01f;
    constexpr float Acf = 1.0f - Hc;
    constexpr float Bcf = -0.5f * Hc * Hc;
    constexpr float T2L = 2.8853900817779268f;  // 2*log2(e)
    constexpr float L2E = 1.4426950408889634f;  // log2(e)
    constexpr float SC1 = 0.5f * Hc;
    constexpr float HH  = 0.5f * Hc;

    const float K0 = Kp[0], K1 = Kp[1], MoV = Mop[0];

    const float A00 = Lp[0], A11 = Lp[5], A22 = Lp[10], A33 = Lp[15];
    const float A01 = 0.5f * (Lp[1]  + Lp[4]);
    const float A02 = 0.5f * (Lp[2]  + Lp[8]);
    const float A03 = 0.5f * (Lp[3]  + Lp[12]);
    const float A12 = 0.5f * (Lp[6]  + Lp[9]);
    const float A13 = 0.5f * (Lp[7]  + Lp[13]);
    const float A23 = 0.5f * (Lp[11] + Lp[14]);

    const bool lo4 = (o < 4);
    const bool odd = (o & 1) != 0;
    // ---- per-lane constants, laundered into pinned VGPRs ----
    float cTf  = lo4 ? (odd ? -Hc : Hc) : 0.0f;     // coeff of partner tanh
    float cUf  = lo4 ? (odd ? HH  : Hc) : 0.0f;     // coeff of u
    float c0f  = (lo4 && odd) ? Bcf : 0.0f;         // f-row additive const
    float cKn  = (o == 2) ? K0 : (o == 3) ? K1 : 0.0f;
    float cwc  = (o == 1) ? Bcf : 0.0f;             // x2-row additive const
    float am   = (o == 0) ? Mp[0] : (o == 1) ? Mp[1] : (o == 2) ? Mp[2] : (o == 3) ? Mp[3] : 0.0f;
    float a0   = (o == 0) ? A00 : (o == 1) ? A11 : (o == 2) ? A22 : (o == 3) ? A33 : 0.0f;
    float a1   = (o == 0) ? A01 : (o == 1) ? A12 : (o == 2) ? A23 : (o == 3) ? A03 : 0.0f;
    float a2   = (o == 0) ? A02 : (o == 1) ? A13 : (o == 2) ? A02 : (o == 3) ? A13 : 0.0f;
    float a3   = (o == 0) ? A03 : (o == 1) ? A01 : (o == 2) ? A12 : (o == 3) ? A23 : 0.0f;
    // shared-transcendental per-lane coefficients:
    //   lanes 0-3: tanh(V [+H/2])  = 1 - 2/(exp2(V*T2L + shift) + 1)
    //   lane  4:   sigma(phi)      = 1 - 1/(exp2(phi*L2E + Mo*L2E) + 1)
    float scE  = lo4 ? T2L : (o == 4) ? L2E : 0.0f;
    float shE  = lo4 ? (odd ? SC1 * T2L : 0.0f) : (o == 4) ? MoV * L2E : 0.0f;
    float cR   = lo4 ? 2.0f : 1.0f;
    // float-mask blends (no per-step v_cmp):
    float mHi  = (o == 2 || o == 3) ? 1.0f : 0.0f;  // F/NH selector
    float mSig = lo4 ? 0.0f : 1.0f;                 // sigmoid-slot selector
    asm volatile("" : "+v"(cTf), "+v"(cUf), "+v"(c0f), "+v"(cKn), "+v"(cwc),
                      "+v"(am), "+v"(a0), "+v"(a1), "+v"(a2), "+v"(a3),
                      "+v"(scE), "+v"(shE), "+v"(cR), "+v"(mHi), "+v"(mSig));

    const float* rw = w + (size_t)b * (2 * NSTEP) + (size_t)(o & 1) * NSTEP;
    const float w_0 = rw[0], w_1 = rw[1], w_T = rw[2046];

    const float th1 = 1.0f - 2.0f * frcp(fexp2(T2L) + 1.0f);        // tanh(1)
    const float thS = 1.0f - 2.0f * frcp(fexp2(SC1 * T2L) + 1.0f);  // tanh(H/2)

    // ---- t = 0 (delta=1, xhat0=(1,0), u0=K0) ----
    float St = (o == 0) ? (Acf + Hc * SC1 + Hc * K0 + w_0)
             : (o == 1) ? (Bcf - Hc * th1 + HH * K0 + w_0)
             : (o == 2) ? 1.0f : 0.0f;
    float TPin = (o == 2) ? thS : (o == 3) ? th1 : 0.0f;
    float U   = K0;
    float SXX = (o == 0) ? 1.0f : 0.0f;
    float SXY = 0.0f;
    float SD  = 1.0f;

    auto step = [&](float wi, bool acc) {
        // F = f(xhat_prev, u_prev) component (lanes 2,3)
        const float cc = __builtin_fmaf(cUf, U, c0f);
        const float F  = __builtin_fmaf(Acf, St, __builtin_fmaf(cTf, TPin, cc));
        const float V  = __builtin_fmaf(mHi, F - St, St);   // rx_o on quad A
        // phi row gather + dot (quad A)
        const float r1 = qperm<ROT1>(V);
        const float r2 = qperm<XOR2>(V);
        const float r3 = qperm<ROT3>(V);
        const float e1 = __builtin_fmaf(a0, V, am);
        const float e2 = a2 * r2;
        const float p1 = __builtin_fmaf(a1, r1, e1);
        const float p2 = __builtin_fmaf(a3, r3, e2);
        const float part = V * (p1 + p2);
        float ps = part + qperm<XOR1>(part);
        ps = ps + qperm<XOR2>(ps);                  // phi (sans Mo) on quad A
        const float phir = qperm<RSHR4>(ps);        // ship to lanes 4-7
        // ONE exp + ONE rcp serves 4 tanh slots + the sigmoid slot
        const float Vmix = __builtin_fmaf(mSig, phir - V, V);
        const float argE = __builtin_fmaf(scE, Vmix, shE);
        const float E  = fexp2(argE);
        const float R  = frcp(E + 1.0f);
        const float tq = __builtin_fmaf(-cR, R, 1.0f);  // lanes0-3: tanh; lane4: delta
        const float dl = qperm<RSHL4>(tq);              // delta onto lanes 0-3
        const float th = tq;
        const float s  = __builtin_fmaf(-th, th, 1.0f); // sech^2
        // u = K.F + delta*K.(X-F): reduces overlap the exp/rcp latency
        const float Dl = r2 - F;                        // lanes2,3: x_partner - F
        const float tF = cKn * F;
        const float tD = cKn * Dl;
        float kF = tF + qperm<XOR1>(tF); kF = kF + qperm<XOR2>(kF);
        float kD = tD + qperm<XOR1>(tD); kD = kD + qperm<XOR2>(kD);
        const float un = __builtin_fmaf(dl, kD, kF);
        if (acc) {
            SXX = __builtin_fmaf(V, V, SXX);
            SXY = __builtin_fmaf(V, r1, SXY);
            SD += dl;
        }
        // xhat update + Taylor-corrected tanh(NH)
        const float d    = dl * Dl;
        const float NH   = F + d;
        const float c2t  = __builtin_fmaf(-d, th, 1.0f);
        const float c1t  = d * s;
        const float th_e = __builtin_fmaf(c1t, c2t, th);
        const float TPx  = qperm<XOR1>(th);    // lanes0,1: partner x-tanh
        TPin = qperm<XOR1>(th_e);              // lanes2,3: partner xhat-tanh
        // x update (lanes 0,1)
        const float cwv = wi + cwc;
        const float Rr  = __builtin_fmaf(Acf, St, __builtin_fmaf(cTf, TPx, cwv));
        const float Xn  = __builtin_fmaf(cUf, un, Rr);
        St = __builtin_fmaf(mHi, NH - Xn, Xn);
        U  = un;
    };

    // t = 1
    step(w_1, true);

    // t = 2 .. 2045: 511 groups of 4; unroll-2 role-swapped double buffer.
    float c0 = rw[2], c1 = rw[3], c2 = rw[4], c3 = rw[5];
    const float* p = rw + 6;
    for (int k = 0; k < 255; ++k) {
        const float n0 = p[0], n1 = p[1], n2 = p[2], n3 = p[3];
        step(c0, true); step(c1, true); step(c2, true); step(c3, true);
        c0 = p[4]; c1 = p[5]; c2 = p[6]; c3 = p[7];
        step(n0, true); step(n1, true); step(n2, true); step(n3, true);
        p += 8;
    }
    step(c0, true); step(c1, true); step(c2, true); step(c3, true);

    // t = 2046
    step(w_T, false);

    // epilogue on quad A
    const float xx    = St * St;
    const float sxx_p = qperm<XOR1>(SXX);
    const float xx_s  = xx + qperm<XOR1>(xx);
    const float suu   = K0 * K0 * SXX + 2.0f * K0 * K1 * SXY + K1 * K1 * sxx_p;
    const float res   = (SXX + sxx_p) + suu + SD + 10.0f * xx_s;
    if (o == 0) out[b] = res;
}

extern "C" void kernel_launch(void* const* d_in, const int* in_sizes, int n_in,
                              void* d_out, int out_size, void* d_ws, size_t ws_size,
                              hipStream_t stream) {
    const float* w  = (const float*)d_in[0];
    const float* K  = (const float*)d_in[1];
    const float* L  = (const float*)d_in[2];
    const float* M  = (const float*)d_in[3];
    const float* Mo = (const float*)d_in[4];
    float* out = (float*)d_out;
    cstr_kernel<<<dim3(8 * NB / 64), dim3(64), 0, stream>>>(w, K, L, M, Mo, out);
}